// Round 7
// baseline (74.870 us; speedup 1.0000x reference)
//
#include <hip/hip_runtime.h>

// out(p) = (49 - g·G)/8,  g = x/max(||x||_C,1e-8),
// G = 7x7 zero-padded box-sum of g (separable 7-tap H then V).
// Single-barrier structure:
//   phase AB: per item load 16 cols x 3ch, normalize in regs, horizontal 7-tap
//             in regs -> write h (bf16 pairs) + center-g slice to LDS
//   barrier
//   phase C : vertical 7-tap running sums from LDS + dot + store
typedef unsigned int u32;
typedef float f32x4 __attribute__((ext_vector_type(4)));

#define EPS2 1e-16f   // 1/max(sqrt(n2),1e-8) == rsq(max(n2,1e-16))

constexpr int TW  = 64;   // out tile width
constexpr int TH  = 32;   // out tile height
constexpr int RIN = 38;   // h rows (TH+6)
constexpr int HSS = 36;   // h row stride, u32 (64 bf16 cols; 144B = 16B mult)
constexpr int GSS = 36;   // gc row stride, u32 (64 bf16 cols)

__device__ __forceinline__ u32 packbf2(float a, float b) {
    // round-half-up bf16 pack (a=lo, b=hi); values bounded, no inf/nan
    const u32 ua = __float_as_uint(a), ub = __float_as_uint(b);
    return ((ua + 0x8000u) >> 16) | ((ub + 0x8000u) & 0xffff0000u);
}
__device__ __forceinline__ float uplo(u32 u) { return __uint_as_float(u << 16); }
__device__ __forceinline__ float uphi(u32 u) { return __uint_as_float(u & 0xffff0000u); }

__global__ __launch_bounds__(256, 5) void mcnd_kernel(const float* __restrict__ x,
                                                      float* __restrict__ out,
                                                      int B, int H, int W) {
    __shared__ __align__(16) u32 hsh[3][RIN][HSS];  // 16,416 B
    __shared__ __align__(16) u32 gsh[3][TH][GSS];   // 13,824 B  (total 30,240)

    const int HW = H * W;
    const int tilesX = W / TW;                      // 8
    const int tilesPerImg = tilesX * (H / TH);      // 128

    // bijective XCD swizzle (grid 4096 % 8 == 0)
    const int cpx = gridDim.x >> 3;
    const int wg  = (blockIdx.x & 7) * cpx + (blockIdx.x >> 3);
    const int b   = wg / tilesPerImg;
    const int t   = wg % tilesPerImg;
    const int ty  = t / tilesX;
    const int tx  = t - ty * tilesX;
    const int y0  = ty * TH;
    const int x0  = tx * TW;

    const float* __restrict__ xb = x + (size_t)b * 3 * HW;
    const int tid = threadIdx.x;

    // ---- phase AB: load 16 cols, normalize, horizontal 7-tap, write h (+gc) ----
    for (int p = tid; p < RIN * 8; p += 256) {
        const int r   = p >> 3;                     // h row (img row y0+r-3)
        const int grp = p & 7;                      // out cols 8grp..8grp+7
        const int gy  = y0 + r - 3;
        const int gx  = x0 + 8 * grp - 4;           // 16B-aligned; cols gx..gx+15
        f32x4 v[3][4];
#pragma unroll
        for (int ch = 0; ch < 3; ++ch)
#pragma unroll
            for (int k = 0; k < 4; ++k) v[ch][k] = f32x4{0.f, 0.f, 0.f, 0.f};
        if (gy >= 0 && gy < H) {
            const float* bp = xb + (size_t)gy * W + gx;
            const bool lok = (gx >= 0);
            const bool rok = (gx + 16 <= W);
#pragma unroll
            for (int ch = 0; ch < 3; ++ch) {
                const float* cp = bp + (size_t)ch * HW;
                if (lok) v[ch][0] = *(const f32x4*)(cp);
                v[ch][1] = *(const f32x4*)(cp + 4);     // always in-image
                v[ch][2] = *(const f32x4*)(cp + 8);     // always in-image
                if (rok) v[ch][3] = *(const f32x4*)(cp + 12);
            }
        }
        // normalize 16 pixels
#pragma unroll
        for (int k = 0; k < 4; ++k) {
            f32x4 n2 = v[0][k]*v[0][k] + v[1][k]*v[1][k] + v[2][k]*v[2][k];
            f32x4 inv;
#pragma unroll
            for (int e = 0; e < 4; ++e)
                inv[e] = __builtin_amdgcn_rsqf(fmaxf(n2[e], EPS2));
            v[0][k] *= inv; v[1][k] *= inv; v[2][k] *= inv;
        }
        // per channel: sliding 7-tap, pack, store
        const bool gcrow = (r >= 3 && r < 35);
#pragma unroll
        for (int ch = 0; ch < 3; ++ch) {
            float c[16];
#pragma unroll
            for (int k = 0; k < 4; ++k)
#pragma unroll
                for (int e = 0; e < 4; ++e) c[4*k + e] = v[ch][k][e];
            // h col 8grp+m (img x0+8grp+m) = sum img cols -3..+3 -> c[m+1..m+7]
            float hp[8];
            hp[0] = c[1]+c[2]+c[3]+c[4]+c[5]+c[6]+c[7];
#pragma unroll
            for (int m = 1; m < 8; ++m) hp[m] = hp[m-1] - c[m] + c[m+7];
            uint4 hw;
            hw.x = packbf2(hp[0], hp[1]); hw.y = packbf2(hp[2], hp[3]);
            hw.z = packbf2(hp[4], hp[5]); hw.w = packbf2(hp[6], hp[7]);
            *(uint4*)&hsh[ch][r][4*grp] = hw;
            if (gcrow) {                            // center g = local cols 4..11
                uint4 gw;
                gw.x = packbf2(c[4],  c[5]);  gw.y = packbf2(c[6],  c[7]);
                gw.z = packbf2(c[8],  c[9]);  gw.w = packbf2(c[10], c[11]);
                *(uint4*)&gsh[ch][r - 3][4*grp] = gw;
            }
        }
    }
    __syncthreads();

    // ---- phase C: vertical 7-tap running sums + dot + store ----
    {
        const int cp = tid & 15;                    // out cols 4cp..4cp+3
        const int rp = tid >> 4;                    // out rows 2rp, 2rp+1
        float D0[4] = {0.f,0.f,0.f,0.f}, D1[4] = {0.f,0.f,0.f,0.f};
#pragma unroll
        for (int ch = 0; ch < 3; ++ch) {
            // rows 2rp..2rp+7 of h cover both out rows' 7-windows
            float s[4] = {0.f,0.f,0.f,0.f};
            float f0[4], f7[4];
#pragma unroll
            for (int d = 0; d < 8; ++d) {
                const uint2 hv = *(const uint2*)&hsh[ch][2*rp + d][2*cp];
                const float a0 = uplo(hv.x), a1 = uphi(hv.x);
                const float a2 = uplo(hv.y), a3 = uphi(hv.y);
                if (d == 0) { f0[0]=a0; f0[1]=a1; f0[2]=a2; f0[3]=a3; }
                if (d == 7) { f7[0]=a0; f7[1]=a1; f7[2]=a2; f7[3]=a3; }
                if (d < 7) { s[0]+=a0; s[1]+=a1; s[2]+=a2; s[3]+=a3; }
            }
            const uint2 g0 = *(const uint2*)&gsh[ch][2*rp][2*cp];
            const uint2 g1 = *(const uint2*)&gsh[ch][2*rp + 1][2*cp];
            const float b0[4] = {uplo(g0.x), uphi(g0.x), uplo(g0.y), uphi(g0.y)};
            const float b1[4] = {uplo(g1.x), uphi(g1.x), uplo(g1.y), uphi(g1.y)};
#pragma unroll
            for (int e = 0; e < 4; ++e) {
                D0[e] += b0[e] * s[e];
                D1[e] += b1[e] * (s[e] - f0[e] + f7[e]);
            }
        }
        f32x4 r0, r1;
#pragma unroll
        for (int e = 0; e < 4; ++e) {
            r0[e] = (49.0f - D0[e]) * 0.125f;
            r1[e] = (49.0f - D1[e]) * 0.125f;
        }
        float* op = out + (size_t)b * HW + (size_t)(y0 + 2*rp) * W + (x0 + 4*cp);
        *(f32x4*)(op)     = r0;                     // lanes 0..15: 256B contiguous
        *(f32x4*)(op + W) = r1;
    }
}

extern "C" void kernel_launch(void* const* d_in, const int* in_sizes, int n_in,
                              void* d_out, int out_size, void* d_ws, size_t ws_size,
                              hipStream_t stream) {
    (void)n_in; (void)d_ws; (void)ws_size; (void)out_size;
    const float* x = (const float*)d_in[0];
    float* out = (float*)d_out;

    const int H = 512, W = 512, C = 3;
    const int B = in_sizes[0] / (C * H * W);        // 32

    const int tilesPerImg = (W / TW) * (H / TH);    // 128
    mcnd_kernel<<<B * tilesPerImg, 256, 0, stream>>>(x, out, B, H, W);
}

// Round 8
// 39.334 us; speedup vs baseline: 1.9034x; 1.9034x over previous
//
#include <hip/hip_runtime.h>

// out(p) = (48 - (g·G - g·g))/8,  g = x/max(||x||_C,1e-8),
// G = 7x7 zero-padded box-sum of g (separable 7-tap H then V).
// Wave-autonomous 64x8 tiles: fused load+normalize+H-pass in registers,
// wave-private bf16 h in LDS, center-g kept packed in registers, one barrier.

typedef unsigned int u32;
typedef float f32x4 __attribute__((ext_vector_type(4)));

#define EPS2 1e-16f   // 1/max(sqrt(n2),1e-8) == rsq(max(n2,1e-16))

constexpr int HR = 14;   // h rows per wave tile (8 out rows + 6 halo)

__device__ __forceinline__ u32 packbf2(float a, float b) {
    // round-half-up bf16 pack (a=lo, b=hi); inputs finite & bounded
    const u32 ua = __float_as_uint(a), ub = __float_as_uint(b);
    return ((ua + 0x8000u) >> 16) | ((ub + 0x8000u) & 0xffff0000u);
}
__device__ __forceinline__ float uplo(u32 u) { return __uint_as_float(u << 16); }
__device__ __forceinline__ float uphi(u32 u) { return __uint_as_float(u & 0xffff0000u); }
__device__ __forceinline__ f32x4 vmul(f32x4 v, float s) {
    f32x4 r; r[0]=v[0]*s; r[1]=v[1]*s; r[2]=v[2]*s; r[3]=v[3]*s; return r;
}

__global__ __launch_bounds__(256, 4) void mcnd_kernel(const float* __restrict__ x,
                                                      float* __restrict__ out,
                                                      int B, int H, int W) {
    // wave-private h: [wave][ch][grp][hr], uint4 = 8 bf16 cols. 21,504 B total.
    __shared__ uint4 hsh[4][3][8][HR];

    const int HW = H * W;
    const int tilesX = W >> 6;                     // 8
    const int tilesPerImg = tilesX * (H >> 5);     // 128

    // bijective XCD swizzle (grid 4096 % 8 == 0)
    const int cpx  = gridDim.x >> 3;
    const int wgid = (blockIdx.x & 7) * cpx + (blockIdx.x >> 3);
    const int b    = wgid / tilesPerImg;
    const int t    = wgid % tilesPerImg;
    const int ty   = t / tilesX;
    const int tx   = t - ty * tilesX;
    const int x0   = tx << 6;

    const int wv   = threadIdx.x >> 6;             // wave id: 8-row strip
    const int lane = threadIdx.x & 63;
    const int r    = lane >> 3;                    // out row within strip
    const int grp  = lane & 7;                     // 8-col group
    const int yw   = (ty << 5) + (wv << 3);        // wave's first out row

    const float* __restrict__ xb = x + (size_t)b * 3 * HW;

    // column geometry for this lane (cols gxl..gxl+15 cover out cols 8grp±halo)
    const int   gxl   = x0 + (grp << 3) - 4;       // 16B-aligned
    const float lmask = (gxl >= 0) ? 1.f : 0.f;
    const float rmask = (gxl + 16 <= W) ? 1.f : 0.f;
    const int   gofL  = (gxl >= 0) ? gxl : 0;              // clamped, in-bounds
    const int   gofR  = (gxl + 16 <= W) ? (gxl + 12) : (W - 4);

    u32 gc0[4], gc1[4], gc2[4];                    // center g, packed bf16

    auto process = [&](int hr, bool capture) {
        const int   gy  = yw + hr - 3;
        const float rmk = (gy >= 0 && gy < H) ? 1.f : 0.f;
        const int   gyc = gy < 0 ? 0 : (gy >= H ? H - 1 : gy);
        const float* rp0 = xb + (size_t)gyc * W;
        const float* rp1 = rp0 + HW;
        const float* rp2 = rp1 + HW;
        // unconditional loads from clamped (always valid) addresses
        f32x4 a0 = *(const f32x4*)(rp0 + gofL);
        f32x4 a1 = *(const f32x4*)(rp0 + gxl + 4);
        f32x4 a2 = *(const f32x4*)(rp0 + gxl + 8);
        f32x4 a3 = *(const f32x4*)(rp0 + gofR);
        f32x4 b0 = *(const f32x4*)(rp1 + gofL);
        f32x4 b1 = *(const f32x4*)(rp1 + gxl + 4);
        f32x4 b2 = *(const f32x4*)(rp1 + gxl + 8);
        f32x4 b3 = *(const f32x4*)(rp1 + gofR);
        f32x4 c0 = *(const f32x4*)(rp2 + gofL);
        f32x4 c1 = *(const f32x4*)(rp2 + gxl + 4);
        f32x4 c2 = *(const f32x4*)(rp2 + gxl + 8);
        f32x4 c3 = *(const f32x4*)(rp2 + gofR);
        // zero the out-of-image column chunks (values are finite -> 0*v == 0)
        a0 = vmul(a0, lmask); b0 = vmul(b0, lmask); c0 = vmul(c0, lmask);
        a3 = vmul(a3, rmask); b3 = vmul(b3, rmask); c3 = vmul(c3, rmask);
        // per-column inverse norm (row mask folded in)
        f32x4 i0, i1, i2, i3;
        {
            const f32x4 n0 = a0*a0 + b0*b0 + c0*c0;
            const f32x4 n1 = a1*a1 + b1*b1 + c1*c1;
            const f32x4 n2 = a2*a2 + b2*b2 + c2*c2;
            const f32x4 n3 = a3*a3 + b3*b3 + c3*c3;
#pragma unroll
            for (int e = 0; e < 4; ++e) {
                i0[e] = __builtin_amdgcn_rsqf(fmaxf(n0[e], EPS2)) * rmk;
                i1[e] = __builtin_amdgcn_rsqf(fmaxf(n1[e], EPS2)) * rmk;
                i2[e] = __builtin_amdgcn_rsqf(fmaxf(n2[e], EPS2)) * rmk;
                i3[e] = __builtin_amdgcn_rsqf(fmaxf(n3[e], EPS2)) * rmk;
            }
        }
        auto chan = [&](const f32x4& A0, const f32x4& A1, const f32x4& A2,
                        const f32x4& A3, int ch, u32* gcp) {
            float cc[16];
#pragma unroll
            for (int e = 0; e < 4; ++e) {
                cc[e]      = A0[e] * i0[e];
                cc[4 + e]  = A1[e] * i1[e];
                cc[8 + e]  = A2[e] * i2[e];
                cc[12 + e] = A3[e] * i3[e];
            }
            // h for out col 8grp+m: staged cols m+1..m+7
            float hp[8];
            hp[0] = cc[1]+cc[2]+cc[3]+cc[4]+cc[5]+cc[6]+cc[7];
#pragma unroll
            for (int m = 1; m < 8; ++m) hp[m] = hp[m-1] - cc[m] + cc[m+7];
            uint4 hwv;
            hwv.x = packbf2(hp[0], hp[1]); hwv.y = packbf2(hp[2], hp[3]);
            hwv.z = packbf2(hp[4], hp[5]); hwv.w = packbf2(hp[6], hp[7]);
            hsh[wv][ch][grp][hr] = hwv;
            if (capture) {                         // center g = local cols 4..11
                gcp[0] = packbf2(cc[4],  cc[5]);
                gcp[1] = packbf2(cc[6],  cc[7]);
                gcp[2] = packbf2(cc[8],  cc[9]);
                gcp[3] = packbf2(cc[10], cc[11]);
            }
        };
        chan(a0, a1, a2, a3, 0, gc0);
        chan(b0, b1, b2, b3, 1, gc1);
        chan(c0, c1, c2, c3, 2, gc2);
    };

    // iter0: hr = r+3 (the lane's own output row -> capture center g)
    process(r + 3, true);
    // iter1: remaining halo rows {0,1,2,11,12,13} on lanes 0..47
    if (lane < 48) {
        const int rr = lane >> 3;                  // 0..5
        process(rr < 3 ? rr : rr + 8, false);
    }
    __syncthreads();

    // ---- vertical 7-tap + dot + store (each h read exactly once per lane) ----
    float D[8] = {0.f,0.f,0.f,0.f,0.f,0.f,0.f,0.f};
    float Q[8] = {0.f,0.f,0.f,0.f,0.f,0.f,0.f,0.f};
    auto vch = [&](int ch, const u32* gcp) {
        float s[8] = {0.f,0.f,0.f,0.f,0.f,0.f,0.f,0.f};
#pragma unroll
        for (int d = 0; d < 7; ++d) {
            const uint4 u = hsh[wv][ch][grp][r + d];
            s[0] += uplo(u.x); s[1] += uphi(u.x);
            s[2] += uplo(u.y); s[3] += uphi(u.y);
            s[4] += uplo(u.z); s[5] += uphi(u.z);
            s[6] += uplo(u.w); s[7] += uphi(u.w);
        }
#pragma unroll
        for (int e = 0; e < 8; ++e) {
            const u32 gu = gcp[e >> 1];
            const float gv = (e & 1) ? uphi(gu) : uplo(gu);
            D[e] += gv * s[e];
            Q[e] += gv * gv;
        }
    };
    vch(0, gc0); vch(1, gc1); vch(2, gc2);

    f32x4 o0, o1;
#pragma unroll
    for (int e = 0; e < 8; ++e) {
        const float v = (48.0f - (D[e] - Q[e])) * 0.125f;
        if (e < 4) o0[e] = v; else o1[e - 4] = v;
    }
    float* op = out + (size_t)b * HW + (size_t)(yw + r) * W + (x0 + (grp << 3));
    *(f32x4*)(op)     = o0;                        // 8 lanes = 256B contiguous
    *(f32x4*)(op + 4) = o1;
}

extern "C" void kernel_launch(void* const* d_in, const int* in_sizes, int n_in,
                              void* d_out, int out_size, void* d_ws, size_t ws_size,
                              hipStream_t stream) {
    (void)n_in; (void)d_ws; (void)ws_size; (void)out_size;
    const float* x = (const float*)d_in[0];
    float* out = (float*)d_out;

    const int H = 512, W = 512, C = 3;
    const int B = in_sizes[0] / (C * H * W);       // 32

    const int tilesPerImg = (W >> 6) * (H >> 5);   // 128
    mcnd_kernel<<<B * tilesPerImg, 256, 0, stream>>>(x, out, B, H, W);
}

// Round 9
// 36.315 us; speedup vs baseline: 2.0617x; 1.0831x over previous
//
#include <hip/hip_runtime.h>

// out(p) = (49 - g·G)/8,  g = x/max(||x||_C,1e-8),
// G = 7x7 zero-padded box-sum of g (separable 7-tap H then V).
// Wave-autonomous 64x8 tiles: fused load+normalize+H-pass in registers,
// wave-private bf16 h in LDS, center-g kept packed in registers.
// NO __syncthreads: each wave reads only its own hsh slice -> a wave-local
// s_waitcnt lgkmcnt(0) suffices (lockstep lanes). HR=15 (odd uint4 stride)
// makes bank-quad = (7*grp + r) mod 8 bijective in grp -> conflict-free.

typedef unsigned int u32;
typedef float f32x4 __attribute__((ext_vector_type(4)));

#define EPS2 1e-16f   // 1/max(sqrt(n2),1e-8) == rsq(max(n2,1e-16))

constexpr int HR = 15;   // 14 h rows (8 out + 6 halo) + 1 pad row (bank swizzle)

__device__ __forceinline__ u32 packbf2(float a, float b) {
    // round-half-up bf16 pack (a=lo, b=hi); inputs finite & bounded
    const u32 ua = __float_as_uint(a), ub = __float_as_uint(b);
    return ((ua + 0x8000u) >> 16) | ((ub + 0x8000u) & 0xffff0000u);
}
__device__ __forceinline__ float uplo(u32 u) { return __uint_as_float(u << 16); }
__device__ __forceinline__ float uphi(u32 u) { return __uint_as_float(u & 0xffff0000u); }
__device__ __forceinline__ f32x4 vmul(f32x4 v, float s) {
    f32x4 r; r[0]=v[0]*s; r[1]=v[1]*s; r[2]=v[2]*s; r[3]=v[3]*s; return r;
}

__global__ __launch_bounds__(256, 4) void mcnd_kernel(const float* __restrict__ x,
                                                      float* __restrict__ out,
                                                      int B, int H, int W) {
    // wave-private h: [wave][ch][grp][hr], uint4 = 8 bf16 cols. 23,040 B total.
    __shared__ uint4 hsh[4][3][8][HR];

    const int HW = H * W;
    const int tilesX = W >> 6;                     // 8
    const int tilesPerImg = tilesX * (H >> 5);     // 128

    // bijective XCD swizzle (grid 4096 % 8 == 0)
    const int cpx  = gridDim.x >> 3;
    const int wgid = (blockIdx.x & 7) * cpx + (blockIdx.x >> 3);
    const int b    = wgid / tilesPerImg;
    const int t    = wgid % tilesPerImg;
    const int ty   = t / tilesX;
    const int tx   = t - ty * tilesX;
    const int x0   = tx << 6;

    const int wv   = threadIdx.x >> 6;             // wave id: 8-row strip
    const int lane = threadIdx.x & 63;
    const int r    = lane >> 3;                    // out row within strip
    const int grp  = lane & 7;                     // 8-col group
    const int yw   = (ty << 5) + (wv << 3);        // wave's first out row

    const float* __restrict__ xb = x + (size_t)b * 3 * HW;

    // column geometry for this lane (cols gxl..gxl+15 cover out cols 8grp±halo)
    const int   gxl   = x0 + (grp << 3) - 4;       // 16B-aligned
    const float lmask = (gxl >= 0) ? 1.f : 0.f;
    const float rmask = (gxl + 16 <= W) ? 1.f : 0.f;
    const int   gofL  = (gxl >= 0) ? gxl : 0;              // clamped, in-bounds
    const int   gofR  = (gxl + 16 <= W) ? (gxl + 12) : (W - 4);

    u32 gc0[4], gc1[4], gc2[4];                    // center g, packed bf16

    auto process = [&](int hr, bool capture) {
        const int   gy  = yw + hr - 3;
        const float rmk = (gy >= 0 && gy < H) ? 1.f : 0.f;
        const int   gyc = gy < 0 ? 0 : (gy >= H ? H - 1 : gy);
        const float* rp0 = xb + (size_t)gyc * W;
        const float* rp1 = rp0 + HW;
        const float* rp2 = rp1 + HW;
        // unconditional loads from clamped (always valid) addresses
        f32x4 a0 = *(const f32x4*)(rp0 + gofL);
        f32x4 a1 = *(const f32x4*)(rp0 + gxl + 4);
        f32x4 a2 = *(const f32x4*)(rp0 + gxl + 8);
        f32x4 a3 = *(const f32x4*)(rp0 + gofR);
        f32x4 b0 = *(const f32x4*)(rp1 + gofL);
        f32x4 b1 = *(const f32x4*)(rp1 + gxl + 4);
        f32x4 b2 = *(const f32x4*)(rp1 + gxl + 8);
        f32x4 b3 = *(const f32x4*)(rp1 + gofR);
        f32x4 c0 = *(const f32x4*)(rp2 + gofL);
        f32x4 c1 = *(const f32x4*)(rp2 + gxl + 4);
        f32x4 c2 = *(const f32x4*)(rp2 + gxl + 8);
        f32x4 c3 = *(const f32x4*)(rp2 + gofR);
        // zero the out-of-image column chunks (values are finite -> 0*v == 0)
        a0 = vmul(a0, lmask); b0 = vmul(b0, lmask); c0 = vmul(c0, lmask);
        a3 = vmul(a3, rmask); b3 = vmul(b3, rmask); c3 = vmul(c3, rmask);
        // per-column inverse norm (row mask folded in)
        f32x4 i0, i1, i2, i3;
        {
            const f32x4 n0 = a0*a0 + b0*b0 + c0*c0;
            const f32x4 n1 = a1*a1 + b1*b1 + c1*c1;
            const f32x4 n2 = a2*a2 + b2*b2 + c2*c2;
            const f32x4 n3 = a3*a3 + b3*b3 + c3*c3;
#pragma unroll
            for (int e = 0; e < 4; ++e) {
                i0[e] = __builtin_amdgcn_rsqf(fmaxf(n0[e], EPS2)) * rmk;
                i1[e] = __builtin_amdgcn_rsqf(fmaxf(n1[e], EPS2)) * rmk;
                i2[e] = __builtin_amdgcn_rsqf(fmaxf(n2[e], EPS2)) * rmk;
                i3[e] = __builtin_amdgcn_rsqf(fmaxf(n3[e], EPS2)) * rmk;
            }
        }
        auto chan = [&](const f32x4& A0, const f32x4& A1, const f32x4& A2,
                        const f32x4& A3, int ch, u32* gcp) {
            float cc[16];
#pragma unroll
            for (int e = 0; e < 4; ++e) {
                cc[e]      = A0[e] * i0[e];
                cc[4 + e]  = A1[e] * i1[e];
                cc[8 + e]  = A2[e] * i2[e];
                cc[12 + e] = A3[e] * i3[e];
            }
            // h for out col 8grp+m: staged cols m+1..m+7
            float hp[8];
            hp[0] = cc[1]+cc[2]+cc[3]+cc[4]+cc[5]+cc[6]+cc[7];
#pragma unroll
            for (int m = 1; m < 8; ++m) hp[m] = hp[m-1] - cc[m] + cc[m+7];
            uint4 hwv;
            hwv.x = packbf2(hp[0], hp[1]); hwv.y = packbf2(hp[2], hp[3]);
            hwv.z = packbf2(hp[4], hp[5]); hwv.w = packbf2(hp[6], hp[7]);
            hsh[wv][ch][grp][hr] = hwv;
            if (capture) {                         // center g = local cols 4..11
                gcp[0] = packbf2(cc[4],  cc[5]);
                gcp[1] = packbf2(cc[6],  cc[7]);
                gcp[2] = packbf2(cc[8],  cc[9]);
                gcp[3] = packbf2(cc[10], cc[11]);
            }
        };
        chan(a0, a1, a2, a3, 0, gc0);
        chan(b0, b1, b2, b3, 1, gc1);
        chan(c0, c1, c2, c3, 2, gc2);
    };

    // iter0: hr = r+3 (the lane's own output row -> capture center g)
    process(r + 3, true);
    // iter1: remaining halo rows {0,1,2,11,12,13} on lanes 0..47
    if (lane < 48) {
        const int rr = lane >> 3;                  // 0..5
        process(rr < 3 ? rr : rr + 8, false);
    }
    // wave-local fence instead of __syncthreads: this wave only reads hsh[wv],
    // written by its own (lockstep) lanes. Order ds_writes before ds_reads.
    asm volatile("s_waitcnt lgkmcnt(0)" ::: "memory");
    __builtin_amdgcn_sched_barrier(0);

    // ---- vertical 7-tap + dot + store (each h read exactly once per lane) ----
    float D[8] = {0.f,0.f,0.f,0.f,0.f,0.f,0.f,0.f};
    auto vch = [&](int ch, const u32* gcp) {
        float s[8] = {0.f,0.f,0.f,0.f,0.f,0.f,0.f,0.f};
#pragma unroll
        for (int d = 0; d < 7; ++d) {
            const uint4 u = hsh[wv][ch][grp][r + d];
            s[0] += uplo(u.x); s[1] += uphi(u.x);
            s[2] += uplo(u.y); s[3] += uphi(u.y);
            s[4] += uplo(u.z); s[5] += uphi(u.z);
            s[6] += uplo(u.w); s[7] += uphi(u.w);
        }
#pragma unroll
        for (int e = 0; e < 8; ++e) {
            const u32 gu = gcp[e >> 1];
            const float gv = (e & 1) ? uphi(gu) : uplo(gu);
            D[e] += gv * s[e];
        }
    };
    vch(0, gc0); vch(1, gc1); vch(2, gc2);

    f32x4 o0, o1;
#pragma unroll
    for (int e = 0; e < 8; ++e) {
        const float v = (49.0f - D[e]) * 0.125f;
        if (e < 4) o0[e] = v; else o1[e - 4] = v;
    }
    float* op = out + (size_t)b * HW + (size_t)(yw + r) * W + (x0 + (grp << 3));
    *(f32x4*)(op)     = o0;                        // 8 lanes = 256B contiguous
    *(f32x4*)(op + 4) = o1;
}

extern "C" void kernel_launch(void* const* d_in, const int* in_sizes, int n_in,
                              void* d_out, int out_size, void* d_ws, size_t ws_size,
                              hipStream_t stream) {
    (void)n_in; (void)d_ws; (void)ws_size; (void)out_size;
    const float* x = (const float*)d_in[0];
    float* out = (float*)d_out;

    const int H = 512, W = 512, C = 3;
    const int B = in_sizes[0] / (C * H * W);       // 32

    const int tilesPerImg = (W >> 6) * (H >> 5);   // 128
    mcnd_kernel<<<B * tilesPerImg, 256, 0, stream>>>(x, out, B, H, W);
}